// Round 15
// baseline (834.221 us; speedup 1.0000x reference)
//
#include <hip/hip_runtime.h>
#include <hip/hip_bf16.h>
#include <math.h>

using v8s   = __attribute__((ext_vector_type(8))) short;
using f32x4 = __attribute__((ext_vector_type(4))) float;

#define DEV __device__ __forceinline__

DEV void gload16(const void* g, void* l) {
  __builtin_amdgcn_global_load_lds(
      (const __attribute__((address_space(1))) unsigned int*)g,
      (__attribute__((address_space(3))) unsigned int*)l,
      16, 0, 0);
}

// ---------------------------------------------------------------- transpose+cast
__global__ __launch_bounds__(256) void transpose_cast(
    const float* __restrict__ in, __hip_bfloat16* __restrict__ out, int K, int N)
{
  __shared__ float tile[32][33];
  const int n0 = blockIdx.x * 32, k0 = blockIdx.y * 32;
  const int tx = threadIdx.x, ty = threadIdx.y;   // 32 x 8
#pragma unroll
  for (int j = 0; j < 4; ++j)
    tile[ty + j*8][tx] = in[(size_t)(k0 + ty + j*8) * N + n0 + tx];
  __syncthreads();
#pragma unroll
  for (int j = 0; j < 4; ++j)
    out[(size_t)(n0 + ty + j*8) * K + k0 + tx] = __float2bfloat16(tile[tx][ty + j*8]);
}

// ---------------------------------------------------------------- layernorm
__global__ __launch_bounds__(256) void ln_kernel(
    const float* __restrict__ xin, const float* __restrict__ g,
    const float* __restrict__ b, __hip_bfloat16* __restrict__ outp)
{
  const int row = blockIdx.x;
  const int t = threadIdx.x;
  const float4 v = ((const float4*)(xin + (size_t)row * 1024))[t];
  float s  = v.x + v.y + v.z + v.w;
  float ss = v.x*v.x + v.y*v.y + v.z*v.z + v.w*v.w;
  for (int off = 32; off > 0; off >>= 1) { s += __shfl_down(s, off); ss += __shfl_down(ss, off); }
  __shared__ float red[8];
  const int w = t >> 6;
  if ((t & 63) == 0) { red[w*2] = s; red[w*2 + 1] = ss; }
  __syncthreads();
  s  = red[0] + red[2] + red[4] + red[6];
  ss = red[1] + red[3] + red[5] + red[7];
  const float mu   = s * (1.0f / 1024.0f);
  const float rstd = rsqrtf(ss * (1.0f / 1024.0f) - mu * mu + 1e-5f);
  const float4 gv = ((const float4*)g)[t];
  const float4 bv = ((const float4*)b)[t];
  __hip_bfloat16* o = outp + (size_t)row * 1024 + t * 4;
  o[0] = __float2bfloat16((v.x - mu) * rstd * gv.x + bv.x);
  o[1] = __float2bfloat16((v.y - mu) * rstd * gv.y + bv.y);
  o[2] = __float2bfloat16((v.z - mu) * rstd * gv.z + bv.z);
  o[3] = __float2bfloat16((v.w - mu) * rstd * gv.w + bv.w);
}

// ---------------------------------------------------------------- 128x128 GEMM (R14 + K-phase stagger)
// Per tile: stage 8 gload16 -> vmcnt(0)+barrier -> 2x{8 ds_read, lgkm(0),
// 16 MFMA} -> barrier. 4 blocks/CU. NEW: per-block K-phase stagger
// (tt = (i + lid) mod NT) desynchronizes co-resident blocks' stage/MFMA
// phases so one block's MFMA covers another's drain (anti-convoy).

#define STAGE_T(tile) do { const int tt_ = (tile);                               \
  _Pragma("unroll") for (int rr_ = 0; rr_ < 4; ++rr_) {                          \
    const int c_ = rr_*256 + t; const int row_ = c_ >> 3; const int sl_ = c_ & 7;\
    const int sw_ = sl_ ^ (row_ & 7);                                            \
    gload16(A + (size_t)(bm0 + row_) * K + tt_*64 + sw_*8, &As[row_][sl_*8]); }  \
  _Pragma("unroll") for (int rr_ = 0; rr_ < 4; ++rr_) {                          \
    const int c_ = rr_*256 + t; const int row_ = c_ >> 3; const int sl_ = c_ & 7;\
    const int sw_ = sl_ ^ (row_ & 7);                                            \
    gload16(Bt + (size_t)(bn0 + row_) * K + tt_*64 + sw_*8, &Bs[row_][sl_*8]); } } while (0)

#define LDAB(k2) do {                                                            \
  _Pragma("unroll") for (int mi_ = 0; mi_ < 4; ++mi_) {                          \
    const int r_ = wm*64 + mi_*16 + lr;                                          \
    a_[mi_] = *(const v8s*)&As[r_][((((k2)*4)+lg) ^ (r_ & 7))*8]; }              \
  _Pragma("unroll") for (int ni_ = 0; ni_ < 4; ++ni_) {                          \
    const int r_ = wn*64 + ni_*16 + lr;                                          \
    b_[ni_] = *(const v8s*)&Bs[r_][((((k2)*4)+lg) ^ (r_ & 7))*8]; } } while (0)

template<int EPI>
__global__ __launch_bounds__(256, 4) void gemm128(
    const __hip_bfloat16* __restrict__ A, const __hip_bfloat16* __restrict__ Bt,
    const float* __restrict__ bias, const float* resid, void* outp,
    __hip_bfloat16* __restrict__ vt, int N, int K, int nbx)
{
  __shared__ __hip_bfloat16 As[128][64];
  __shared__ __hip_bfloat16 Bs[128][64];

  const int t = threadIdx.x;
  const int w = t >> 6, l = t & 63;
  const int wm = w >> 1, wn = w & 1;
  const int lr = l & 15, lg = l >> 4;

  // XCD supergroup mapping: nby = 128 (M=16384); nbx % 4 == 0.
  const int xcd  = blockIdx.x & 7;
  const int lid  = blockIdx.x >> 3;
  const int super = lid >> 5;
  const int rem   = lid & 31;
  const int nsx   = nbx >> 2;
  const int gy    = super / nsx;
  const int gx    = super - gy * nsx;
  const int by    = xcd * 16 + gy * 8 + (rem >> 2);
  const int bx    = gx * 4 + (rem & 3);
  const size_t bm0 = (size_t)by * 128, bn0 = (size_t)bx * 128;

  const int NT = K >> 6;               // 16 or 64 (power of 2)
  const int phase = lid & (NT - 1);    // anti-convoy K-phase stagger

  const f32x4 zz = {0.f, 0.f, 0.f, 0.f};
  f32x4 acc[4][4];
#pragma unroll
  for (int i = 0; i < 4; ++i)
#pragma unroll
    for (int j = 0; j < 4; ++j) acc[i][j] = zz;

  v8s a_[4], b_[4];
  for (int ii = 0; ii < NT; ++ii) {
    const int tt = (ii + phase) & (NT - 1);
    STAGE_T(tt);
    asm volatile("s_waitcnt vmcnt(0)" ::: "memory");
    __builtin_amdgcn_s_barrier();
    __builtin_amdgcn_sched_barrier(0);
#pragma unroll
    for (int k2 = 0; k2 < 2; ++k2) {
      LDAB(k2);
      asm volatile("s_waitcnt lgkmcnt(0)" ::: "memory");
      __builtin_amdgcn_sched_barrier(0);
      __builtin_amdgcn_s_setprio(1);
#pragma unroll
      for (int mi = 0; mi < 4; ++mi)
#pragma unroll
        for (int ni = 0; ni < 4; ++ni)
          acc[mi][ni] = __builtin_amdgcn_mfma_f32_16x16x32_bf16(a_[mi], b_[ni], acc[mi][ni], 0, 0, 0);
      __builtin_amdgcn_s_setprio(0);
    }
    __builtin_amdgcn_s_barrier();
    __builtin_amdgcn_sched_barrier(0);
  }

#pragma unroll
  for (int m = 0; m < 4; ++m)
#pragma unroll
    for (int n = 0; n < 4; ++n) {
      const int col = (int)bn0 + wn * 64 + n * 16 + lr;
      const float bz = bias[col];
#pragma unroll
      for (int r = 0; r < 4; ++r) {
        const int row = (int)bm0 + wm * 64 + m * 16 + lg * 4 + r;
        const float v = acc[m][n][r] + bz;
        if (EPI == 1) {
          ((float*)outp)[(size_t)row * N + col] = v + resid[(size_t)row * N + col];
        } else if (EPI == 2) {
          const float gel = 0.5f * v * (1.0f + erff(v * 0.70710678118654752f));
          ((__hip_bfloat16*)outp)[(size_t)row * N + col] = __float2bfloat16(gel);
        } else {
          if (col < 2048) {
            // fold softmax scale * log2(e) into Q (exp2-domain attention)
            const float vv = (col < 1024) ? v * 0.18033688011112042f : v;
            ((__hip_bfloat16*)outp)[(size_t)row * 3072 + col] = __float2bfloat16(vv);
          } else {
            const int d = col - 2048;
            const int hh = d >> 6, dd = d & 63;
            const int bbq = row >> 10, nn = row & 1023;
            // pi-permuted token order to match packed-P contraction order
            const int nnp = (nn & ~31) | (((nn & 15) << 1) | ((nn >> 4) & 1));
            vt[(((size_t)bbq * 16 + hh) * 64 + dd) * 1024 + nnp] = __float2bfloat16(v);
          }
        }
      }
    }
}

// ---------------------------------------------------------------- flash attention v6 (R13-passing, unchanged)
__global__ __launch_bounds__(512) void attn_kernel(
    const __hip_bfloat16* __restrict__ qkv, const __hip_bfloat16* __restrict__ vt,
    __hip_bfloat16* __restrict__ ctx)
{
  __shared__ __hip_bfloat16 Ks[2][64 * 64];  // [buf][n][d], slot s at s^(n&7)
  __shared__ __hip_bfloat16 Vs[2][64 * 64];  // [buf][d][pi(n)], slot s at s^(d&7)
  __shared__ __hip_bfloat16 Ps[8][32][72];   // per-wave P, padded stride 144B

  const int t = threadIdx.x;
  const int w = t >> 6, l = t & 63;          // w: 0..7
  const int lr = l & 15, lg = l >> 4;

  const int lin  = blockIdx.x;               // 0..1023
  const int xcd  = lin & 7;
  const int slot = lin >> 3;                 // 0..127
  const int head = xcd * 32 + (slot >> 2);   // 0..255
  const int q0   = (slot & 3) * 256;
  const int bb = head >> 4, h = head & 15;
  const int tok0 = bb * 1024;
  const int qrow_base = tok0 + q0 + w * 32;

  const int srow0 = t >> 3, ssl0 = t & 7, ssw0 = ssl0 ^ (srow0 & 7);

  v8s qf[2][2];
#pragma unroll
  for (int i = 0; i < 2; ++i)
#pragma unroll
    for (int k2 = 0; k2 < 2; ++k2)
      qf[i][k2] = *(const v8s*)(qkv + (size_t)(qrow_base + i * 16 + lr) * 3072 + h * 64 + k2 * 32 + lg * 8);

  v8s vone;
#pragma unroll
  for (int e = 0; e < 8; ++e) vone[e] = (short)0x3F80;

  const f32x4 zz = {0.f, 0.f, 0.f, 0.f};
  f32x4 oacc[2][5];                 // [..][4] = row-sum l
#pragma unroll
  for (int i = 0; i < 2; ++i)
#pragma unroll
    for (int dg = 0; dg < 5; ++dg) oacc[i][dg] = zz;

  {
    gload16(qkv + (size_t)(tok0 + srow0) * 3072 + 1024 + h * 64 + ssw0 * 8, &Ks[0][t * 8]);
    gload16(vt  + (size_t)(head * 64 + srow0) * 1024 + ssw0 * 8,            &Vs[0][t * 8]);
  }
  asm volatile("s_waitcnt vmcnt(0)" ::: "memory");
  __builtin_amdgcn_s_barrier();

  for (int kt = 0; kt < 16; ++kt) {
    const int cur = kt & 1;
    if (kt < 15) {
      const int nxt = cur ^ 1;
      const int kn = (kt + 1) * 64;
      gload16(qkv + (size_t)(tok0 + kn + srow0) * 3072 + 1024 + h * 64 + ssw0 * 8, &Ks[nxt][t * 8]);
      gload16(vt  + (size_t)(head * 64 + srow0) * 1024 + kn + ssw0 * 8,            &Vs[nxt][t * 8]);
    }

    f32x4 s[2][4];
#pragma unroll
    for (int i = 0; i < 2; ++i)
#pragma unroll
      for (int j = 0; j < 4; ++j) s[i][j] = zz;
#pragma unroll
    for (int k2 = 0; k2 < 2; ++k2) {
      v8s kb[4];
#pragma unroll
      for (int j = 0; j < 4; ++j) {
        const int row = j * 16 + lr;
        kb[j] = *(const v8s*)(&Ks[cur][row * 64 + (((k2 * 4 + lg) ^ (row & 7)) * 8)]);
      }
#pragma unroll
      for (int i = 0; i < 2; ++i)
#pragma unroll
        for (int j = 0; j < 4; ++j)
          s[i][j] = __builtin_amdgcn_mfma_f32_16x16x32_bf16(qf[i][k2], kb[j], s[i][j], 0, 0, 0);
    }

#pragma unroll
    for (int i = 0; i < 2; ++i)
#pragma unroll
      for (int jj = 0; jj < 2; ++jj)
#pragma unroll
        for (int r = 0; r < 4; ++r) {
          const float lo = exp2f(s[i][2*jj][r]);
          const float hi = exp2f(s[i][2*jj + 1][r]);
          unsigned int pk;
          asm("v_cvt_pk_bf16_f32 %0, %1, %2" : "=v"(pk) : "v"(lo), "v"(hi));
          *(unsigned int*)&Ps[w][i * 16 + lg * 4 + r][jj * 32 + lr * 2] = pk;
        }

#pragma unroll
    for (int k2 = 0; k2 < 2; ++k2) {
      v8s pa[2];
#pragma unroll
      for (int i = 0; i < 2; ++i)
        pa[i] = *(const v8s*)&Ps[w][i * 16 + lr][k2 * 32 + lg * 8];
#pragma unroll
      for (int dg = 0; dg < 4; ++dg) {
        const int row = dg * 16 + lr;
        v8s vb = *(const v8s*)(&Vs[cur][row * 64 + (((k2 * 4 + lg) ^ (row & 7)) * 8)]);
#pragma unroll
        for (int i = 0; i < 2; ++i)
          oacc[i][dg] = __builtin_amdgcn_mfma_f32_16x16x32_bf16(pa[i], vb, oacc[i][dg], 0, 0, 0);
      }
#pragma unroll
      for (int i = 0; i < 2; ++i)
        oacc[i][4] = __builtin_amdgcn_mfma_f32_16x16x32_bf16(pa[i], vone, oacc[i][4], 0, 0, 0);
    }

    asm volatile("s_waitcnt vmcnt(0)" ::: "memory");
    __builtin_amdgcn_s_barrier();
  }

#pragma unroll
  for (int i = 0; i < 2; ++i) {
    float inv[4];
#pragma unroll
    for (int r = 0; r < 4; ++r) inv[r] = 1.0f / oacc[i][4][r];
#pragma unroll
    for (int dg = 0; dg < 4; ++dg)
#pragma unroll
      for (int r = 0; r < 4; ++r) {
        const int qrow = qrow_base + i * 16 + lg * 4 + r;
        ctx[(size_t)qrow * 1024 + h * 64 + dg * 16 + lr] = __float2bfloat16(oacc[i][dg][r] * inv[r]);
      }
  }
}

// ---------------------------------------------------------------- launch
extern "C" void kernel_launch(void* const* d_in, const int* in_sizes, int n_in,
                              void* d_out, int out_size, void* d_ws, size_t ws_size,
                              hipStream_t stream) {
  const float* x      = (const float*)d_in[0];
  const float* ln1_g  = (const float*)d_in[1];
  const float* ln1_b  = (const float*)d_in[2];
  const float* w_qkv  = (const float*)d_in[3];
  const float* b_qkv  = (const float*)d_in[4];
  const float* w_proj = (const float*)d_in[5];
  const float* b_proj = (const float*)d_in[6];
  const float* ln2_g  = (const float*)d_in[7];
  const float* ln2_b  = (const float*)d_in[8];
  const float* w_fc1  = (const float*)d_in[9];
  const float* b_fc1  = (const float*)d_in[10];
  const float* w_fc2  = (const float*)d_in[11];
  const float* b_fc2  = (const float*)d_in[12];
  float* out = (float*)d_out;

  char* ws = (char*)d_ws;
  size_t off = 0;
  auto alloc = [&](size_t bytes) { char* p = ws + off; off += bytes; return p; };
  __hip_bfloat16* wqkvt  = (__hip_bfloat16*)alloc((size_t)3072 * 1024 * 2);
  __hip_bfloat16* wprojt = (__hip_bfloat16*)alloc((size_t)1024 * 1024 * 2);
  __hip_bfloat16* wfc1t  = (__hip_bfloat16*)alloc((size_t)4096 * 1024 * 2);
  __hip_bfloat16* wfc2t  = (__hip_bfloat16*)alloc((size_t)1024 * 4096 * 2);
  __hip_bfloat16* h      = (__hip_bfloat16*)alloc((size_t)16384 * 1024 * 2);
  __hip_bfloat16* qkvb   = (__hip_bfloat16*)alloc((size_t)16384 * 3072 * 2);
  __hip_bfloat16* vt     = (__hip_bfloat16*)alloc((size_t)256 * 64 * 1024 * 2);
  __hip_bfloat16* ctx    = (__hip_bfloat16*)alloc((size_t)16384 * 1024 * 2);
  __hip_bfloat16* mbuf   = qkvb;

  transpose_cast<<<dim3(3072/32, 1024/32), dim3(32, 8), 0, stream>>>(w_qkv,  wqkvt,  1024, 3072);
  transpose_cast<<<dim3(1024/32, 1024/32), dim3(32, 8), 0, stream>>>(w_proj, wprojt, 1024, 1024);
  transpose_cast<<<dim3(4096/32, 1024/32), dim3(32, 8), 0, stream>>>(w_fc1,  wfc1t,  1024, 4096);
  transpose_cast<<<dim3(1024/32, 4096/32), dim3(32, 8), 0, stream>>>(w_fc2,  wfc2t,  4096, 1024);

  ln_kernel<<<16384, 256, 0, stream>>>(x, ln1_g, ln1_b, h);
  gemm128<3><<<16 * 24 * 8, 256, 0, stream>>>(h,    wqkvt,  b_qkv,  nullptr, qkvb,  vt,      3072, 1024, 24);
  attn_kernel<<<1024, 512, 0, stream>>>(qkvb, vt, ctx);
  gemm128<1><<<16 *  8 * 8, 256, 0, stream>>>(ctx,  wprojt, b_proj, x,       d_out, nullptr, 1024, 1024, 8);
  ln_kernel<<<16384, 256, 0, stream>>>(out, ln2_g, ln2_b, h);
  gemm128<2><<<16 * 32 * 8, 256, 0, stream>>>(h,    wfc1t,  b_fc1,  nullptr, mbuf,  nullptr, 4096, 1024, 32);
  gemm128<1><<<16 *  8 * 8, 256, 0, stream>>>(mbuf, wfc2t,  b_fc2,  out,     d_out, nullptr, 1024, 4096, 8);
}

// Round 16
// 701.688 us; speedup vs baseline: 1.1889x; 1.1889x over previous
//
#include <hip/hip_runtime.h>
#include <hip/hip_bf16.h>
#include <math.h>

using v8s   = __attribute__((ext_vector_type(8))) short;
using f32x4 = __attribute__((ext_vector_type(4))) float;

#define DEV __device__ __forceinline__

DEV void gload16(const void* g, void* l) {
  __builtin_amdgcn_global_load_lds(
      (const __attribute__((address_space(1))) unsigned int*)g,
      (__attribute__((address_space(3))) unsigned int*)l,
      16, 0, 0);
}

// ---------------------------------------------------------------- transpose+cast
__global__ __launch_bounds__(256) void transpose_cast(
    const float* __restrict__ in, __hip_bfloat16* __restrict__ out, int K, int N)
{
  __shared__ float tile[32][33];
  const int n0 = blockIdx.x * 32, k0 = blockIdx.y * 32;
  const int tx = threadIdx.x, ty = threadIdx.y;   // 32 x 8
#pragma unroll
  for (int j = 0; j < 4; ++j)
    tile[ty + j*8][tx] = in[(size_t)(k0 + ty + j*8) * N + n0 + tx];
  __syncthreads();
#pragma unroll
  for (int j = 0; j < 4; ++j)
    out[(size_t)(n0 + ty + j*8) * K + k0 + tx] = __float2bfloat16(tile[tx][ty + j*8]);
}

// ---------------------------------------------------------------- layernorm
__global__ __launch_bounds__(256) void ln_kernel(
    const float* __restrict__ xin, const float* __restrict__ g,
    const float* __restrict__ b, __hip_bfloat16* __restrict__ outp)
{
  const int row = blockIdx.x;
  const int t = threadIdx.x;
  const float4 v = ((const float4*)(xin + (size_t)row * 1024))[t];
  float s  = v.x + v.y + v.z + v.w;
  float ss = v.x*v.x + v.y*v.y + v.z*v.z + v.w*v.w;
  for (int off = 32; off > 0; off >>= 1) { s += __shfl_down(s, off); ss += __shfl_down(ss, off); }
  __shared__ float red[8];
  const int w = t >> 6;
  if ((t & 63) == 0) { red[w*2] = s; red[w*2 + 1] = ss; }
  __syncthreads();
  s  = red[0] + red[2] + red[4] + red[6];
  ss = red[1] + red[3] + red[5] + red[7];
  const float mu   = s * (1.0f / 1024.0f);
  const float rstd = rsqrtf(ss * (1.0f / 1024.0f) - mu * mu + 1e-5f);
  const float4 gv = ((const float4*)g)[t];
  const float4 bv = ((const float4*)b)[t];
  __hip_bfloat16* o = outp + (size_t)row * 1024 + t * 4;
  o[0] = __float2bfloat16((v.x - mu) * rstd * gv.x + bv.x);
  o[1] = __float2bfloat16((v.y - mu) * rstd * gv.y + bv.y);
  o[2] = __float2bfloat16((v.z - mu) * rstd * gv.z + bv.z);
  o[3] = __float2bfloat16((v.w - mu) * rstd * gv.w + bv.w);
}

// ---------------------------------------------------------------- 128x128 GEMM (R14 config: m97 structure + swizzle + XCD supergroups)
// Per tile: stage 8 gload16 -> vmcnt(0)+barrier -> 2x{8 ds_read, lgkm(0),
// 16 MFMA} -> barrier. 4 blocks/CU; phase-aligned blocks share the same
// K-slice (L2-resident, ~192KB/supergroup). NOTE (R15 lesson): do NOT
// K-stagger blocks -- the "convoy" IS the L2 locality (stagger -> 6.5x FETCH).

#define STAGE_T(tile) do { const int tt_ = (tile);                               \
  _Pragma("unroll") for (int rr_ = 0; rr_ < 4; ++rr_) {                          \
    const int c_ = rr_*256 + t; const int row_ = c_ >> 3; const int sl_ = c_ & 7;\
    const int sw_ = sl_ ^ (row_ & 7);                                            \
    gload16(A + (size_t)(bm0 + row_) * K + tt_*64 + sw_*8, &As[row_][sl_*8]); }  \
  _Pragma("unroll") for (int rr_ = 0; rr_ < 4; ++rr_) {                          \
    const int c_ = rr_*256 + t; const int row_ = c_ >> 3; const int sl_ = c_ & 7;\
    const int sw_ = sl_ ^ (row_ & 7);                                            \
    gload16(Bt + (size_t)(bn0 + row_) * K + tt_*64 + sw_*8, &Bs[row_][sl_*8]); } } while (0)

#define LDAB(k2) do {                                                            \
  _Pragma("unroll") for (int mi_ = 0; mi_ < 4; ++mi_) {                          \
    const int r_ = wm*64 + mi_*16 + lr;                                          \
    a_[mi_] = *(const v8s*)&As[r_][((((k2)*4)+lg) ^ (r_ & 7))*8]; }              \
  _Pragma("unroll") for (int ni_ = 0; ni_ < 4; ++ni_) {                          \
    const int r_ = wn*64 + ni_*16 + lr;                                          \
    b_[ni_] = *(const v8s*)&Bs[r_][((((k2)*4)+lg) ^ (r_ & 7))*8]; } } while (0)

template<int EPI>
__global__ __launch_bounds__(256, 4) void gemm128(
    const __hip_bfloat16* __restrict__ A, const __hip_bfloat16* __restrict__ Bt,
    const float* __restrict__ bias, const float* resid, void* outp,
    __hip_bfloat16* __restrict__ vt, int N, int K, int nbx)
{
  __shared__ __hip_bfloat16 As[128][64];
  __shared__ __hip_bfloat16 Bs[128][64];

  const int t = threadIdx.x;
  const int w = t >> 6, l = t & 63;
  const int wm = w >> 1, wn = w & 1;
  const int lr = l & 15, lg = l >> 4;

  // XCD supergroup mapping: nby = 128 (M=16384); nbx % 4 == 0.
  const int xcd  = blockIdx.x & 7;
  const int lid  = blockIdx.x >> 3;
  const int super = lid >> 5;
  const int rem   = lid & 31;
  const int nsx   = nbx >> 2;
  const int gy    = super / nsx;
  const int gx    = super - gy * nsx;
  const int by    = xcd * 16 + gy * 8 + (rem >> 2);
  const int bx    = gx * 4 + (rem & 3);
  const size_t bm0 = (size_t)by * 128, bn0 = (size_t)bx * 128;

  const int NT = K >> 6;

  const f32x4 zz = {0.f, 0.f, 0.f, 0.f};
  f32x4 acc[4][4];
#pragma unroll
  for (int i = 0; i < 4; ++i)
#pragma unroll
    for (int j = 0; j < 4; ++j) acc[i][j] = zz;

  v8s a_[4], b_[4];
  for (int tt = 0; tt < NT; ++tt) {
    STAGE_T(tt);
    asm volatile("s_waitcnt vmcnt(0)" ::: "memory");
    __builtin_amdgcn_s_barrier();
    __builtin_amdgcn_sched_barrier(0);
#pragma unroll
    for (int k2 = 0; k2 < 2; ++k2) {
      LDAB(k2);
      asm volatile("s_waitcnt lgkmcnt(0)" ::: "memory");
      __builtin_amdgcn_sched_barrier(0);
      __builtin_amdgcn_s_setprio(1);
#pragma unroll
      for (int mi = 0; mi < 4; ++mi)
#pragma unroll
        for (int ni = 0; ni < 4; ++ni)
          acc[mi][ni] = __builtin_amdgcn_mfma_f32_16x16x32_bf16(a_[mi], b_[ni], acc[mi][ni], 0, 0, 0);
      __builtin_amdgcn_s_setprio(0);
    }
    __builtin_amdgcn_s_barrier();   // all reads retired before next stage
    __builtin_amdgcn_sched_barrier(0);
  }

#pragma unroll
  for (int m = 0; m < 4; ++m)
#pragma unroll
    for (int n = 0; n < 4; ++n) {
      const int col = (int)bn0 + wn * 64 + n * 16 + lr;
      const float bz = bias[col];
#pragma unroll
      for (int r = 0; r < 4; ++r) {
        const int row = (int)bm0 + wm * 64 + m * 16 + lg * 4 + r;
        const float v = acc[m][n][r] + bz;
        if (EPI == 1) {
          ((float*)outp)[(size_t)row * N + col] = v + resid[(size_t)row * N + col];
        } else if (EPI == 2) {
          const float gel = 0.5f * v * (1.0f + erff(v * 0.70710678118654752f));
          ((__hip_bfloat16*)outp)[(size_t)row * N + col] = __float2bfloat16(gel);
        } else {
          if (col < 2048) {
            // fold softmax scale * log2(e) into Q (exp2-domain attention)
            const float vv = (col < 1024) ? v * 0.18033688011112042f : v;
            ((__hip_bfloat16*)outp)[(size_t)row * 3072 + col] = __float2bfloat16(vv);
          } else {
            const int d = col - 2048;
            const int hh = d >> 6, dd = d & 63;
            const int bbq = row >> 10, nn = row & 1023;
            // pi-permuted token order to match packed-P contraction order
            const int nnp = (nn & ~31) | (((nn & 15) << 1) | ((nn >> 4) & 1));
            vt[(((size_t)bbq * 16 + hh) * 64 + dd) * 1024 + nnp] = __float2bfloat16(v);
          }
        }
      }
    }
}

// ---------------------------------------------------------------- flash attention v6 (R13/R14-passing, unchanged)
__global__ __launch_bounds__(512) void attn_kernel(
    const __hip_bfloat16* __restrict__ qkv, const __hip_bfloat16* __restrict__ vt,
    __hip_bfloat16* __restrict__ ctx)
{
  __shared__ __hip_bfloat16 Ks[2][64 * 64];  // [buf][n][d], slot s at s^(n&7)
  __shared__ __hip_bfloat16 Vs[2][64 * 64];  // [buf][d][pi(n)], slot s at s^(d&7)
  __shared__ __hip_bfloat16 Ps[8][32][72];   // per-wave P, padded stride 144B

  const int t = threadIdx.x;
  const int w = t >> 6, l = t & 63;          // w: 0..7
  const int lr = l & 15, lg = l >> 4;

  const int lin  = blockIdx.x;               // 0..1023
  const int xcd  = lin & 7;
  const int slot = lin >> 3;                 // 0..127
  const int head = xcd * 32 + (slot >> 2);   // 0..255
  const int q0   = (slot & 3) * 256;
  const int bb = head >> 4, h = head & 15;
  const int tok0 = bb * 1024;
  const int qrow_base = tok0 + q0 + w * 32;

  const int srow0 = t >> 3, ssl0 = t & 7, ssw0 = ssl0 ^ (srow0 & 7);

  v8s qf[2][2];
#pragma unroll
  for (int i = 0; i < 2; ++i)
#pragma unroll
    for (int k2 = 0; k2 < 2; ++k2)
      qf[i][k2] = *(const v8s*)(qkv + (size_t)(qrow_base + i * 16 + lr) * 3072 + h * 64 + k2 * 32 + lg * 8);

  v8s vone;
#pragma unroll
  for (int e = 0; e < 8; ++e) vone[e] = (short)0x3F80;

  const f32x4 zz = {0.f, 0.f, 0.f, 0.f};
  f32x4 oacc[2][5];                 // [..][4] = row-sum l
#pragma unroll
  for (int i = 0; i < 2; ++i)
#pragma unroll
    for (int dg = 0; dg < 5; ++dg) oacc[i][dg] = zz;

  {
    gload16(qkv + (size_t)(tok0 + srow0) * 3072 + 1024 + h * 64 + ssw0 * 8, &Ks[0][t * 8]);
    gload16(vt  + (size_t)(head * 64 + srow0) * 1024 + ssw0 * 8,            &Vs[0][t * 8]);
  }
  asm volatile("s_waitcnt vmcnt(0)" ::: "memory");
  __builtin_amdgcn_s_barrier();

  for (int kt = 0; kt < 16; ++kt) {
    const int cur = kt & 1;
    if (kt < 15) {
      const int nxt = cur ^ 1;
      const int kn = (kt + 1) * 64;
      gload16(qkv + (size_t)(tok0 + kn + srow0) * 3072 + 1024 + h * 64 + ssw0 * 8, &Ks[nxt][t * 8]);
      gload16(vt  + (size_t)(head * 64 + srow0) * 1024 + kn + ssw0 * 8,            &Vs[nxt][t * 8]);
    }

    f32x4 s[2][4];
#pragma unroll
    for (int i = 0; i < 2; ++i)
#pragma unroll
      for (int j = 0; j < 4; ++j) s[i][j] = zz;
#pragma unroll
    for (int k2 = 0; k2 < 2; ++k2) {
      v8s kb[4];
#pragma unroll
      for (int j = 0; j < 4; ++j) {
        const int row = j * 16 + lr;
        kb[j] = *(const v8s*)(&Ks[cur][row * 64 + (((k2 * 4 + lg) ^ (row & 7)) * 8)]);
      }
#pragma unroll
      for (int i = 0; i < 2; ++i)
#pragma unroll
        for (int j = 0; j < 4; ++j)
          s[i][j] = __builtin_amdgcn_mfma_f32_16x16x32_bf16(qf[i][k2], kb[j], s[i][j], 0, 0, 0);
    }

#pragma unroll
    for (int i = 0; i < 2; ++i)
#pragma unroll
      for (int jj = 0; jj < 2; ++jj)
#pragma unroll
        for (int r = 0; r < 4; ++r) {
          const float lo = exp2f(s[i][2*jj][r]);
          const float hi = exp2f(s[i][2*jj + 1][r]);
          unsigned int pk;
          asm("v_cvt_pk_bf16_f32 %0, %1, %2" : "=v"(pk) : "v"(lo), "v"(hi));
          *(unsigned int*)&Ps[w][i * 16 + lg * 4 + r][jj * 32 + lr * 2] = pk;
        }

#pragma unroll
    for (int k2 = 0; k2 < 2; ++k2) {
      v8s pa[2];
#pragma unroll
      for (int i = 0; i < 2; ++i)
        pa[i] = *(const v8s*)&Ps[w][i * 16 + lr][k2 * 32 + lg * 8];
#pragma unroll
      for (int dg = 0; dg < 4; ++dg) {
        const int row = dg * 16 + lr;
        v8s vb = *(const v8s*)(&Vs[cur][row * 64 + (((k2 * 4 + lg) ^ (row & 7)) * 8)]);
#pragma unroll
        for (int i = 0; i < 2; ++i)
          oacc[i][dg] = __builtin_amdgcn_mfma_f32_16x16x32_bf16(pa[i], vb, oacc[i][dg], 0, 0, 0);
      }
#pragma unroll
      for (int i = 0; i < 2; ++i)
        oacc[i][4] = __builtin_amdgcn_mfma_f32_16x16x32_bf16(pa[i], vone, oacc[i][4], 0, 0, 0);
    }

    asm volatile("s_waitcnt vmcnt(0)" ::: "memory");
    __builtin_amdgcn_s_barrier();
  }

#pragma unroll
  for (int i = 0; i < 2; ++i) {
    float inv[4];
#pragma unroll
    for (int r = 0; r < 4; ++r) inv[r] = 1.0f / oacc[i][4][r];
#pragma unroll
    for (int dg = 0; dg < 4; ++dg)
#pragma unroll
      for (int r = 0; r < 4; ++r) {
        const int qrow = qrow_base + i * 16 + lg * 4 + r;
        ctx[(size_t)qrow * 1024 + h * 64 + dg * 16 + lr] = __float2bfloat16(oacc[i][dg][r] * inv[r]);
      }
  }
}

// ---------------------------------------------------------------- launch
extern "C" void kernel_launch(void* const* d_in, const int* in_sizes, int n_in,
                              void* d_out, int out_size, void* d_ws, size_t ws_size,
                              hipStream_t stream) {
  const float* x      = (const float*)d_in[0];
  const float* ln1_g  = (const float*)d_in[1];
  const float* ln1_b  = (const float*)d_in[2];
  const float* w_qkv  = (const float*)d_in[3];
  const float* b_qkv  = (const float*)d_in[4];
  const float* w_proj = (const float*)d_in[5];
  const float* b_proj = (const float*)d_in[6];
  const float* ln2_g  = (const float*)d_in[7];
  const float* ln2_b  = (const float*)d_in[8];
  const float* w_fc1  = (const float*)d_in[9];
  const float* b_fc1  = (const float*)d_in[10];
  const float* w_fc2  = (const float*)d_in[11];
  const float* b_fc2  = (const float*)d_in[12];
  float* out = (float*)d_out;

  char* ws = (char*)d_ws;
  size_t off = 0;
  auto alloc = [&](size_t bytes) { char* p = ws + off; off += bytes; return p; };
  __hip_bfloat16* wqkvt  = (__hip_bfloat16*)alloc((size_t)3072 * 1024 * 2);
  __hip_bfloat16* wprojt = (__hip_bfloat16*)alloc((size_t)1024 * 1024 * 2);
  __hip_bfloat16* wfc1t  = (__hip_bfloat16*)alloc((size_t)4096 * 1024 * 2);
  __hip_bfloat16* wfc2t  = (__hip_bfloat16*)alloc((size_t)1024 * 4096 * 2);
  __hip_bfloat16* h      = (__hip_bfloat16*)alloc((size_t)16384 * 1024 * 2);
  __hip_bfloat16* qkvb   = (__hip_bfloat16*)alloc((size_t)16384 * 3072 * 2);
  __hip_bfloat16* vt     = (__hip_bfloat16*)alloc((size_t)256 * 64 * 1024 * 2);
  __hip_bfloat16* ctx    = (__hip_bfloat16*)alloc((size_t)16384 * 1024 * 2);
  __hip_bfloat16* mbuf   = qkvb;

  transpose_cast<<<dim3(3072/32, 1024/32), dim3(32, 8), 0, stream>>>(w_qkv,  wqkvt,  1024, 3072);
  transpose_cast<<<dim3(1024/32, 1024/32), dim3(32, 8), 0, stream>>>(w_proj, wprojt, 1024, 1024);
  transpose_cast<<<dim3(4096/32, 1024/32), dim3(32, 8), 0, stream>>>(w_fc1,  wfc1t,  1024, 4096);
  transpose_cast<<<dim3(1024/32, 4096/32), dim3(32, 8), 0, stream>>>(w_fc2,  wfc2t,  4096, 1024);

  ln_kernel<<<16384, 256, 0, stream>>>(x, ln1_g, ln1_b, h);
  gemm128<3><<<16 * 24 * 8, 256, 0, stream>>>(h,    wqkvt,  b_qkv,  nullptr, qkvb,  vt,      3072, 1024, 24);
  attn_kernel<<<1024, 512, 0, stream>>>(qkvb, vt, ctx);
  gemm128<1><<<16 *  8 * 8, 256, 0, stream>>>(ctx,  wprojt, b_proj, x,       d_out, nullptr, 1024, 1024, 8);
  ln_kernel<<<16384, 256, 0, stream>>>(out, ln2_g, ln2_b, h);
  gemm128<2><<<16 * 32 * 8, 256, 0, stream>>>(h,    wfc1t,  b_fc1,  nullptr, mbuf,  nullptr, 4096, 1024, 32);
  gemm128<1><<<16 *  8 * 8, 256, 0, stream>>>(mbuf, wfc2t,  b_fc2,  out,     d_out, nullptr, 1024, 4096, 8);
}